// Round 14
// baseline (1506.507 us; speedup 1.0000x reference)
//
#include <hip/hip_runtime.h>

#define CAP 128   // padded-ELL row capacity; max degree ~60 for Poisson(32)

typedef __bf16 bf16x8 __attribute__((ext_vector_type(8)));
typedef float  f32x4  __attribute__((ext_vector_type(4)));

__device__ __forceinline__ unsigned short f2bf(float f) {
  unsigned int u = __float_as_uint(f);
  unsigned int r = (u + 0x7FFFu + ((u >> 16) & 1u)) >> 16;
  return (unsigned short)r;
}
__device__ __forceinline__ float bf2f(unsigned short u) {
  return __uint_as_float(((unsigned int)u) << 16);
}
__device__ __forceinline__ void gload_lds16(const void* g, void* l) {
  __builtin_amdgcn_global_load_lds(
      (const __attribute__((address_space(1))) unsigned int*)g,
      (__attribute__((address_space(3))) unsigned int*)l, 16, 0, 0);
}

// ---------------- x cast+pad: X[M][K] f32 -> Xb[M][Kp] bf16, zero-padded (vectorized x4) ----
__global__ __launch_bounds__(256)
void cast_pad_bf16(const float* __restrict__ X, unsigned short* __restrict__ Xb,
                   int M, int K, int Kp) {
  int k4 = blockIdx.x * 256 + threadIdx.x;      // index in units of 4 elems
  int r = blockIdx.y;
  int k = k4 * 4;
  if (k >= Kp) return;
  ushort4 o;
  if (k + 4 <= K) {
    float4 v = *reinterpret_cast<const float4*>(X + (size_t)r * K + k);
    o.x = f2bf(v.x); o.y = f2bf(v.y); o.z = f2bf(v.z); o.w = f2bf(v.w);
  } else {
    float vv[4];
    #pragma unroll
    for (int j = 0; j < 4; ++j) vv[j] = (k + j < K) ? X[(size_t)r * K + k + j] : 0.f;
    o.x = f2bf(vv[0]); o.y = f2bf(vv[1]); o.z = f2bf(vv[2]); o.w = f2bf(vv[3]);
  }
  *reinterpret_cast<ushort4*>(Xb + (size_t)r * Kp + k) = o;
}

// ---------------- weight transpose + cast:  W[K][Nv] f32 -> Wt[Nv][Kp] bf16 ----
__global__ __launch_bounds__(256)
void transpose_cast(const float* __restrict__ W, unsigned short* __restrict__ Wt,
                    int K, int Nv, int Kp) {
  __shared__ float tile[32][33];
  int kb = blockIdx.x * 32, nb = blockIdx.y * 32;
  int tx = threadIdx.x, ty = threadIdx.y;   // 32 x 8
  for (int i = ty; i < 32; i += 8) {
    int k = kb + i, n = nb + tx;
    tile[i][tx] = (k < K && n < Nv) ? W[(size_t)k * Nv + n] : 0.f;
  }
  __syncthreads();
  for (int i = ty; i < 32; i += 8) {
    int n = nb + i, k = kb + tx;
    if (n < Nv && k < Kp) Wt[(size_t)n * Kp + k] = f2bf(tile[tx][i]);
  }
}

// ---------------- padded-ELL build (packed col+val) ----------------
__global__ __launch_bounds__(256)
void ell_build(const int* __restrict__ erows, const int* __restrict__ ecols,
               const float* __restrict__ evals, int* __restrict__ cnt,
               int2* __restrict__ ecv, int E) {
  int e = blockIdx.x * 256 + threadIdx.x;
  if (e >= E) return;
  int r = erows[e];
  int slot = atomicAdd(&cnt[r], 1);
  if (slot < CAP)
    ecv[(size_t)r * CAP + slot] = make_int2(ecols[e], __float_as_int(evals[e]));
}

// ---------------- SpMM, bf16 gather, 4 elems/thread, 8x-unrolled gather ----
template<bool RELU, bool BIAS, bool OUTBF>
__global__ __launch_bounds__(256)
void spmm_b(const unsigned short* __restrict__ S, const int* __restrict__ cnt,
            const int2* __restrict__ ecv, const float* __restrict__ bias,
            void* __restrict__ outp, int nv /*dim/4*/, int ldo4) {
  __shared__ int2 eb[CAP];
  int r = blockIdx.x, t = threadIdx.x, nt = blockDim.x;
  int c = cnt[r]; if (c > CAP) c = CAP;
  for (int j = t; j < c; j += nt) eb[j] = ecv[(size_t)r * CAP + j];
  __syncthreads();
  if (t >= nv) {
    if (OUTBF && t < ldo4) {  // zero K-pad columns for the consuming GEMM
      ushort4 z; z.x = z.y = z.z = z.w = 0;
      ((ushort4*)outp)[(size_t)r * ldo4 + t] = z;
    }
    return;
  }
  const ushort4* S4 = (const ushort4*)S;
  float ax = 0.f, ay = 0.f, az = 0.f, aw = 0.f;
  int j = 0;
  for (; j + 8 <= c; j += 8) {   // 8 independent gathers in flight (L3-latency MLP)
    ushort4 s[8]; float v[8];
    #pragma unroll
    for (int q = 0; q < 8; ++q) {
      int2 e = eb[j + q];
      s[q] = S4[(size_t)e.x * nv + t];
      v[q] = __int_as_float(e.y);
    }
    #pragma unroll
    for (int q = 0; q < 8; ++q) {
      ax += v[q] * bf2f(s[q].x); ay += v[q] * bf2f(s[q].y);
      az += v[q] * bf2f(s[q].z); aw += v[q] * bf2f(s[q].w);
    }
  }
  for (; j < c; ++j) {
    int col = eb[j].x; float v = __int_as_float(eb[j].y);
    ushort4 s = S4[(size_t)col * nv + t];
    ax += v * bf2f(s.x); ay += v * bf2f(s.y); az += v * bf2f(s.z); aw += v * bf2f(s.w);
  }
  if (BIAS) {
    float4 bb = ((const float4*)bias)[t];
    ax += bb.x; ay += bb.y; az += bb.z; aw += bb.w;
  }
  if (RELU) { ax = fmaxf(ax, 0.f); ay = fmaxf(ay, 0.f); az = fmaxf(az, 0.f); aw = fmaxf(aw, 0.f); }
  if (OUTBF) {
    ushort4 o; o.x = f2bf(ax); o.y = f2bf(ay); o.z = f2bf(az); o.w = f2bf(aw);
    ((ushort4*)outp)[(size_t)r * ldo4 + t] = o;
  } else {
    ((float4*)outp)[(size_t)r * nv + t] = make_float4(ax, ay, az, aw);
  }
}

// ---------------- SpMM, f32 gather ----------------
template<bool RELU, bool BIAS, bool OUTBF>
__global__ __launch_bounds__(256)
void spmm_f(const float* __restrict__ S, const int* __restrict__ cnt,
            const int2* __restrict__ ecv, const float* __restrict__ bias,
            void* __restrict__ outp, int nv, int ldo4) {
  __shared__ int2 eb[CAP];
  int r = blockIdx.x, t = threadIdx.x, nt = blockDim.x;
  int c = cnt[r]; if (c > CAP) c = CAP;
  for (int j = t; j < c; j += nt) eb[j] = ecv[(size_t)r * CAP + j];
  __syncthreads();
  if (t >= nv) {
    if (OUTBF && t < ldo4) {
      ushort4 z; z.x = z.y = z.z = z.w = 0;
      ((ushort4*)outp)[(size_t)r * ldo4 + t] = z;
    }
    return;
  }
  const float4* S4 = (const float4*)S;
  float ax = 0.f, ay = 0.f, az = 0.f, aw = 0.f;
  for (int j = 0; j < c; ++j) {
    int col = eb[j].x; float v = __int_as_float(eb[j].y);
    float4 s = S4[(size_t)col * nv + t];
    ax += v * s.x; ay += v * s.y; az += v * s.z; aw += v * s.w;
  }
  if (BIAS) {
    float4 bb = ((const float4*)bias)[t];
    ax += bb.x; ay += bb.y; az += bb.z; aw += bb.w;
  }
  if (RELU) { ax = fmaxf(ax, 0.f); ay = fmaxf(ay, 0.f); az = fmaxf(az, 0.f); aw = fmaxf(aw, 0.f); }
  if (OUTBF) {
    ushort4 o; o.x = f2bf(ax); o.y = f2bf(ay); o.z = f2bf(az); o.w = f2bf(aw);
    ((ushort4*)outp)[(size_t)r * ldo4 + t] = o;
  } else {
    ((float4*)outp)[(size_t)r * nv + t] = make_float4(ax, ay, az, aw);
  }
}

// ---------------- GEMM narrow (128x128, BK=32, r10-proven) for N <= 512 ----------------
template<bool RELU, bool BIAS, bool OUTBF>
__global__ __launch_bounds__(512)
void gemm_bf16(const unsigned short* __restrict__ A, int LDA,
               const unsigned short* __restrict__ Bt, int LDB,
               const float* __restrict__ bias, void* __restrict__ Cp, int LDC,
               int M, int Nv, int NBX, int K) {
  if ((int)blockIdx.x >= NBX) return;
  __shared__ unsigned short As[3][128 * 32];
  __shared__ unsigned short Bs[3][128 * 32];
  int n0 = blockIdx.x * 128, m0 = blockIdx.y * 128;
  int t = threadIdx.x, w = t >> 6, l = t & 63;
  int wr = (w >> 2) * 64;        // 2 wave-rows (M)
  int wc = (w & 3) * 32;         // 4 wave-cols (N)
  int lr = l & 15, lhi = l >> 4;

  f32x4 acc[4][2] = {};

  int scol = ((t & 3) ^ ((t >> 3) & 3)) * 8;
  const unsigned short* ga0 = A + (size_t)(m0 + (t >> 2)) * LDA + scol;
  const unsigned short* gb0 = Bt + (size_t)(n0 + (t >> 2)) * LDB + scol;

  int nk = K >> 5;

#define STAGE(tile, Ab, Bb) do {                                \
    gload_lds16(ga0 + (size_t)(tile) * 32, (Ab) + t * 8);       \
    gload_lds16(gb0 + (size_t)(tile) * 32, (Bb) + t * 8);       \
  } while (0)

  STAGE(0, As[0], Bs[0]);
  if (nk > 1) STAGE(1, As[1], Bs[1]);

  int c0 = 0, c1 = 1, c2 = 2;
  for (int kt = 0; kt < nk; ++kt) {
    if (kt + 1 < nk) asm volatile("s_waitcnt vmcnt(2)" ::: "memory");
    else             asm volatile("s_waitcnt vmcnt(0)" ::: "memory");
    __builtin_amdgcn_sched_barrier(0);
    __builtin_amdgcn_s_barrier();
    __builtin_amdgcn_sched_barrier(0);
    if (kt + 2 < nk) STAGE(kt + 2, As[c2], Bs[c2]);

    const unsigned short* Ab = As[c0];
    const unsigned short* Bb = Bs[c0];
    bf16x8 af[4], bfr[2];
    int rchunk = (lhi ^ ((lr >> 1) & 3)) * 8;
    #pragma unroll
    for (int i = 0; i < 4; ++i) af[i] = *(const bf16x8*)&Ab[(wr + i * 16 + lr) * 32 + rchunk];
    #pragma unroll
    for (int j = 0; j < 2; ++j) bfr[j] = *(const bf16x8*)&Bb[(wc + j * 16 + lr) * 32 + rchunk];
    __builtin_amdgcn_s_setprio(1);
    #pragma unroll
    for (int i = 0; i < 4; ++i)
      #pragma unroll
      for (int j = 0; j < 2; ++j) {
        if (OUTBF)
          acc[i][j] = __builtin_amdgcn_mfma_f32_16x16x32_bf16(bfr[j], af[i], acc[i][j], 0, 0, 0);
        else
          acc[i][j] = __builtin_amdgcn_mfma_f32_16x16x32_bf16(af[i], bfr[j], acc[i][j], 0, 0, 0);
      }
    __builtin_amdgcn_s_setprio(0);

    int tmp = c0; c0 = c1; c1 = c2; c2 = tmp;
  }
#undef STAGE

  if (OUTBF) {
    #pragma unroll
    for (int i = 0; i < 4; ++i) {
      int grow = m0 + wr + i * 16 + lr;
      if (grow >= M) continue;
      #pragma unroll
      for (int j = 0; j < 2; ++j) {
        int gcol = n0 + wc + j * 16 + lhi * 4;
        if (gcol >= Nv) continue;
        f32x4 v = acc[i][j];
        float v0 = v[0], v1 = v[1], v2 = v[2], v3 = v[3];
        if (BIAS) { v0 += bias[gcol]; v1 += bias[gcol + 1]; v2 += bias[gcol + 2]; v3 += bias[gcol + 3]; }
        if (RELU) { v0 = fmaxf(v0, 0.f); v1 = fmaxf(v1, 0.f); v2 = fmaxf(v2, 0.f); v3 = fmaxf(v3, 0.f); }
        ushort4 o; o.x = f2bf(v0); o.y = f2bf(v1); o.z = f2bf(v2); o.w = f2bf(v3);
        *(ushort4*)((unsigned short*)Cp + (size_t)grow * LDC + gcol) = o;
      }
    }
  } else {
    int cr = lhi * 4, cc = lr;
    #pragma unroll
    for (int i = 0; i < 4; ++i) {
      #pragma unroll
      for (int j = 0; j < 2; ++j) {
        int gcol = n0 + wc + j * 16 + cc;
        if (gcol >= Nv) continue;
        float bv = BIAS ? bias[gcol] : 0.f;
        #pragma unroll
        for (int q = 0; q < 4; ++q) {
          int grow = m0 + wr + i * 16 + cr + q;
          if (grow >= M) continue;
          float v = acc[i][j][q] + bv;
          if (RELU) v = fmaxf(v, 0.f);
          ((float*)Cp)[(size_t)grow * LDC + gcol] = v;
        }
      }
    }
  }
}

// ---------------- GEMM tall (256x128, BK=32) for N >= 1024 ----------------
// 8 waves each own a 64x64 quadrant (acc[4][4], 16 MFMA/K-step): per-wave LDS reads
// 8 KB per K-step for 262k FLOP = 32.8 FLOP/B (+50% vs narrow's 21.8) -- r13 PMC
// showed LDS-read traffic ~51% busy is the largest cost component. Staged bytes/FLOP
// -25%. Same depth-3 counted-vmcnt (3 loads/thread -> vmcnt(3)), same swizzle
// (row offsets +64/+128/+192 preserve (row>>1)&3 == (lr>>1)&3, algebra checked),
// same orientation-conditional epilogue. 72 KB LDS -> 2 blocks/CU (16 waves).
// Only used when blocks >= ~600 (N>=1024 layers) to avoid r11's imbalance trap.
template<bool RELU, bool BIAS, bool OUTBF>
__global__ __launch_bounds__(512)
void gemm_tall(const unsigned short* __restrict__ A, int LDA,
               const unsigned short* __restrict__ Bt, int LDB,
               const float* __restrict__ bias, void* __restrict__ Cp, int LDC,
               int M, int Nv, int NBX, int K) {
  if ((int)blockIdx.x >= NBX) return;
  __shared__ unsigned short As[3][256 * 32];
  __shared__ unsigned short Bs[3][128 * 32];
  int n0 = blockIdx.x * 128, m0 = blockIdx.y * 256;
  int t = threadIdx.x, w = t >> 6, l = t & 63;
  int wr = (w >> 1) * 64;        // 4 wave-rows (M)
  int wc = (w & 1) * 64;         // 2 wave-cols (N)
  int lr = l & 15, lhi = l >> 4;

  f32x4 acc[4][4] = {};

  int scol = ((t & 3) ^ ((t >> 3) & 3)) * 8;
  const unsigned short* ga0 = A + (size_t)(m0 + (t >> 2)) * LDA + scol;
  const unsigned short* ga1 = A + (size_t)(m0 + 128 + (t >> 2)) * LDA + scol;
  const unsigned short* gb0 = Bt + (size_t)(n0 + (t >> 2)) * LDB + scol;

  int nk = K >> 5;

#define STAGET(tile, Ab, Bb) do {                                   \
    gload_lds16(ga0 + (size_t)(tile) * 32, (Ab) + t * 8);           \
    gload_lds16(ga1 + (size_t)(tile) * 32, (Ab) + 4096 + t * 8);    \
    gload_lds16(gb0 + (size_t)(tile) * 32, (Bb) + t * 8);           \
  } while (0)

  STAGET(0, As[0], Bs[0]);
  if (nk > 1) STAGET(1, As[1], Bs[1]);

  int c0 = 0, c1 = 1, c2 = 2;
  for (int kt = 0; kt < nk; ++kt) {
    if (kt + 1 < nk) asm volatile("s_waitcnt vmcnt(3)" ::: "memory");
    else             asm volatile("s_waitcnt vmcnt(0)" ::: "memory");
    __builtin_amdgcn_sched_barrier(0);
    __builtin_amdgcn_s_barrier();
    __builtin_amdgcn_sched_barrier(0);
    if (kt + 2 < nk) STAGET(kt + 2, As[c2], Bs[c2]);

    const unsigned short* Ab = As[c0];
    const unsigned short* Bb = Bs[c0];
    bf16x8 af[4], bfr[4];
    int rchunk = (lhi ^ ((lr >> 1) & 3)) * 8;
    #pragma unroll
    for (int i = 0; i < 4; ++i) af[i] = *(const bf16x8*)&Ab[(wr + i * 16 + lr) * 32 + rchunk];
    #pragma unroll
    for (int j = 0; j < 4; ++j) bfr[j] = *(const bf16x8*)&Bb[(wc + j * 16 + lr) * 32 + rchunk];
    __builtin_amdgcn_s_setprio(1);
    #pragma unroll
    for (int i = 0; i < 4; ++i)
      #pragma unroll
      for (int j = 0; j < 4; ++j) {
        if (OUTBF)
          acc[i][j] = __builtin_amdgcn_mfma_f32_16x16x32_bf16(bfr[j], af[i], acc[i][j], 0, 0, 0);
        else
          acc[i][j] = __builtin_amdgcn_mfma_f32_16x16x32_bf16(af[i], bfr[j], acc[i][j], 0, 0, 0);
      }
    __builtin_amdgcn_s_setprio(0);

    int tmp = c0; c0 = c1; c1 = c2; c2 = tmp;
  }
#undef STAGET

  if (OUTBF) {
    #pragma unroll
    for (int i = 0; i < 4; ++i) {
      int grow = m0 + wr + i * 16 + lr;
      if (grow >= M) continue;
      #pragma unroll
      for (int j = 0; j < 4; ++j) {
        int gcol = n0 + wc + j * 16 + lhi * 4;
        if (gcol >= Nv) continue;
        f32x4 v = acc[i][j];
        float v0 = v[0], v1 = v[1], v2 = v[2], v3 = v[3];
        if (BIAS) { v0 += bias[gcol]; v1 += bias[gcol + 1]; v2 += bias[gcol + 2]; v3 += bias[gcol + 3]; }
        if (RELU) { v0 = fmaxf(v0, 0.f); v1 = fmaxf(v1, 0.f); v2 = fmaxf(v2, 0.f); v3 = fmaxf(v3, 0.f); }
        ushort4 o; o.x = f2bf(v0); o.y = f2bf(v1); o.z = f2bf(v2); o.w = f2bf(v3);
        *(ushort4*)((unsigned short*)Cp + (size_t)grow * LDC + gcol) = o;
      }
    }
  } else {
    int cr = lhi * 4, cc = lr;
    #pragma unroll
    for (int i = 0; i < 4; ++i) {
      #pragma unroll
      for (int j = 0; j < 4; ++j) {
        int gcol = n0 + wc + j * 16 + cc;
        if (gcol >= Nv) continue;
        float bv = BIAS ? bias[gcol] : 0.f;
        #pragma unroll
        for (int q = 0; q < 4; ++q) {
          int grow = m0 + wr + i * 16 + cr + q;
          if (grow >= M) continue;
          float v = acc[i][j][q] + bv;
          if (RELU) v = fmaxf(v, 0.f);
          ((float*)Cp)[(size_t)grow * LDC + gcol] = v;
        }
      }
    }
  }
}

// ---------------- fallback GEMM (register staging) ----------------
template<bool RELU, bool BIAS, bool ABF>
__global__ __launch_bounds__(256)
void gemm_old(const void* __restrict__ Ap, const unsigned short* __restrict__ Bt,
              const float* __restrict__ bias, float* __restrict__ C,
              int M, int K, int Kp, int Nv) {
  __shared__ unsigned short As[128][40];
  __shared__ unsigned short Bs[128][40];
  int m0 = blockIdx.x * 128, n0 = blockIdx.y * 128;
  int t = threadIdx.x;
  int w = t >> 6, l = t & 63;
  int wr = (w >> 1) * 64, wc = (w & 1) * 64;
  int lr = l & 15, lk = (l >> 4) * 8;
  f32x4 acc[4][4] = {};
  int srow = t >> 1;
  int skg  = (t & 1) * 16;
  int nk = (K + 31) / 32;
  for (int kt = 0; kt < nk; ++kt) {
    int k0 = kt * 32;
    {
      int gm = m0 + srow;
      unsigned short* dst = &As[srow][skg];
      if (ABF) {
        uint4 v0 = make_uint4(0,0,0,0), v1 = make_uint4(0,0,0,0);
        if (gm < M) {
          const uint4* src = reinterpret_cast<const uint4*>(
              (const unsigned short*)Ap + (size_t)gm * Kp + k0 + skg);
          v0 = src[0]; v1 = src[1];
        }
        reinterpret_cast<uint4*>(dst)[0] = v0;
        reinterpret_cast<uint4*>(dst)[1] = v1;
      } else {
        const float* A = (const float*)Ap;
        const float* src = A + (size_t)gm * K + k0 + skg;
        if (gm < M && (K & 3) == 0 && k0 + skg + 16 <= K) {
          #pragma unroll
          for (int j = 0; j < 4; ++j) {
            float4 v = reinterpret_cast<const float4*>(src)[j];
            unsigned int lo = (unsigned int)f2bf(v.x) | ((unsigned int)f2bf(v.y) << 16);
            unsigned int hi = (unsigned int)f2bf(v.z) | ((unsigned int)f2bf(v.w) << 16);
            reinterpret_cast<uint2*>(dst)[j] = make_uint2(lo, hi);
          }
        } else {
          for (int j = 0; j < 16; ++j) {
            int k = k0 + skg + j;
            float v = (gm < M && k < K) ? A[(size_t)gm * K + k] : 0.f;
            dst[j] = f2bf(v);
          }
        }
      }
    }
    {
      int gn = n0 + srow;
      unsigned short* dst = &Bs[srow][skg];
      if (gn < Nv && k0 + skg + 16 <= Kp) {
        const uint4* src = reinterpret_cast<const uint4*>(Bt + (size_t)gn * Kp + k0 + skg);
        reinterpret_cast<uint4*>(dst)[0] = src[0];
        reinterpret_cast<uint4*>(dst)[1] = src[1];
      } else {
        for (int j = 0; j < 16; ++j) {
          int k = k0 + skg + j;
          dst[j] = (gn < Nv && k < Kp) ? Bt[(size_t)gn * Kp + k] : (unsigned short)0;
        }
      }
    }
    __syncthreads();
    bf16x8 a[4], b[4];
    #pragma unroll
    for (int i = 0; i < 4; ++i) a[i] = *reinterpret_cast<const bf16x8*>(&As[wr + i * 16 + lr][lk]);
    #pragma unroll
    for (int j = 0; j < 4; ++j) b[j] = *reinterpret_cast<const bf16x8*>(&Bs[wc + j * 16 + lr][lk]);
    #pragma unroll
    for (int i = 0; i < 4; ++i)
      #pragma unroll
      for (int j = 0; j < 4; ++j)
        acc[i][j] = __builtin_amdgcn_mfma_f32_16x16x32_bf16(a[i], b[j], acc[i][j], 0, 0, 0);
    __syncthreads();
  }
  int cr = (l >> 4) * 4, cc = l & 15;
  #pragma unroll
  for (int i = 0; i < 4; ++i) {
    #pragma unroll
    for (int j = 0; j < 4; ++j) {
      int gcol = n0 + wc + j * 16 + cc;
      if (gcol >= Nv) continue;
      float bv = BIAS ? bias[gcol] : 0.f;
      #pragma unroll
      for (int q = 0; q < 4; ++q) {
        int grow = m0 + wr + i * 16 + cr + q;
        if (grow >= M) continue;
        float v = acc[i][j][q] + bv;
        if (RELU) v = fmaxf(v, 0.f);
        C[(size_t)grow * Nv + gcol] = v;
      }
    }
  }
}

// ------------------------------------------------------------------------------------
extern "C" void kernel_launch(void* const* d_in, const int* in_sizes, int n_in,
                              void* d_out, int out_size, void* d_ws, size_t ws_size,
                              hipStream_t stream) {
  const float* x        = (const float*)d_in[0];
  const int*   erows    = (const int*)d_in[1];
  const int*   ecols_in = (const int*)d_in[2];
  const float* evals_in = (const float*)d_in[3];
  const float* w[8]; const float* bia[8];
  for (int i = 0; i < 8; ++i) { w[i] = (const float*)d_in[4 + 2 * i]; bia[i] = (const float*)d_in[5 + 2 * i]; }

  const int IN_DIM = 3703;
  const int M = in_sizes[0] / IN_DIM;       // 20000
  const int E = in_sizes[1];                // 640000
  const int Kd[8] = {3703, 1024, 512, 256,   16, 256, 512, 1024};
  const int Nd[8] = {1024,  512, 256,  16,  256, 512, 1024, 3703};
  int Kp[8], Nvp[8];
  for (int i = 0; i < 8; ++i) { Kp[i] = (Kd[i] + 63) & ~63; Nvp[i] = (Nd[i] + 127) & ~127; }

  auto al = [](size_t v) { return (v + 255) & ~(size_t)255; };
  size_t wtB[8], wtTot = 0;
  for (int i = 0; i < 8; ++i) { wtB[i] = al((size_t)Nvp[i] * Kp[i] * 2); wtTot += wtB[i]; }
  size_t cntB = al((size_t)M * 4), ecvB = al((size_t)M * CAP * 8);
  size_t xbfB = al((size_t)M * Kp[0] * 2);
  size_t a1B  = al((size_t)M * 1024 * 2);
  size_t pbB  = al((size_t)M * 1024 * 2);
  size_t grdB = 4 << 20;   // covers 256-row m-tail OOB staging reads (max ~1.7 MB)
  bool fast = (wtTot + cntB + ecvB + xbfB + a1B + pbB + grdB) <= ws_size;

  float* Z  = (float*)d_out;                    // M x 16
  float* XR = (float*)d_out + (size_t)M * 16;   // M x 3703

  if (fast) {
    char* p = (char*)d_ws;
    auto alloc = [&](size_t bytes) { char* r = p; p += al(bytes); return r; };
    unsigned short* Wt[8];
    for (int i = 0; i < 8; ++i) Wt[i] = (unsigned short*)alloc(wtB[i]);
    int*  cnt = (int*)alloc(cntB);
    int2* ecv = (int2*)alloc(ecvB);
    unsigned short* Xbf = (unsigned short*)alloc(xbfB);  // m-tail OOB reads spill into A1
    unsigned short* A1  = (unsigned short*)alloc(a1B);   // ... into Pb
    unsigned short* Pb  = (unsigned short*)alloc(pbB);   // ... into guard
    alloc(grdB);

    hipMemsetAsync(cnt, 0, (size_t)M * 4, stream);
    ell_build<<<(E + 255) / 256, 256, 0, stream>>>(erows, ecols_in, evals_in, cnt, ecv, E);
    for (int i = 0; i < 8; ++i) {
      dim3 g((Kp[i] + 31) / 32, (Nd[i] + 31) / 32);
      transpose_cast<<<g, dim3(32, 8), 0, stream>>>(w[i], Wt[i], Kd[i], Nd[i], Kp[i]);
    }
    { dim3 g((Kp[0] / 4 + 255) / 256, M);
      cast_pad_bf16<<<g, 256, 0, stream>>>(x, Xbf, M, IN_DIM, Kp[0]); }

    auto gemmB = [&](const unsigned short* A, int lda, int li, const float* bb,
                     void* C, int ldc, bool relu, bool bias_on, bool outbf) {
      int nbx = (Nd[li] + 127) / 128;
      if (Nd[li] >= 1024) {   // tall 256x128 kernel: e0, d2, d3 (>=600 blocks)
        dim3 g((unsigned)((nbx + 7) & ~7), (unsigned)((M + 255) / 256));
        if (outbf) {
          if (relu)
            gemm_tall<true, true, true><<<g, 512, 0, stream>>>(A, lda, Wt[li], Kp[li], bb, C, ldc, M, Nd[li], nbx, Kp[li]);
          else
            gemm_tall<false, false, true><<<g, 512, 0, stream>>>(A, lda, Wt[li], Kp[li], nullptr, C, ldc, M, Nd[li], nbx, Kp[li]);
        } else {
          gemm_tall<false, true, false><<<g, 512, 0, stream>>>(A, lda, Wt[li], Kp[li], bb, C, ldc, M, Nd[li], nbx, Kp[li]);
        }
      } else {                // narrow 128x128 kernel (r10/r12-proven)
        dim3 g((unsigned)((nbx + 7) & ~7), (unsigned)((M + 127) / 128));
        if (outbf) {
          if (relu)
            gemm_bf16<true, true, true><<<g, 512, 0, stream>>>(A, lda, Wt[li], Kp[li], bb, C, ldc, M, Nd[li], nbx, Kp[li]);
          else
            gemm_bf16<false, false, true><<<g, 512, 0, stream>>>(A, lda, Wt[li], Kp[li], nullptr, C, ldc, M, Nd[li], nbx, Kp[li]);
        } else {
          gemm_bf16<false, true, false><<<g, 512, 0, stream>>>(A, lda, Wt[li], Kp[li], bb, C, ldc, M, Nd[li], nbx, Kp[li]);
        }
      }
    };
    auto spmm4 = [&](const unsigned short* S, const float* bb, void* out,
                     int dim, int ldo4, bool relu, bool bias_on, bool outbf) {
      int nv = dim >> 2;
      int thr = (nv > ldo4 ? nv : ldo4); thr = (thr + 63) & ~63; if (thr > 256) thr = 256;
      if (outbf) {
        if (relu) spmm_b<true, true, true><<<M, thr, 0, stream>>>(S, cnt, ecv, bb, out, nv, ldo4);
        else      spmm_b<false, false, true><<<M, thr, 0, stream>>>(S, cnt, ecv, nullptr, out, nv, ldo4);
      } else {
        spmm_b<false, true, false><<<M, thr, 0, stream>>>(S, cnt, ecv, bb, out, nv, nv);
      }
    };

    // ---- encoder: support = H@W (bf16), agg = A*support (+bias, relu, bf16) ----
    gemmB(Xbf, Kp[0], 0, nullptr, Pb, 1024, false, false, true);
    spmm4(Pb, bia[0], A1, 1024, Kp[1] / 4, true, true, true);   // stride 1024 == Kp[1]
    gemmB(A1, Kp[1], 1, nullptr, Pb, 512, false, false, true);
    spmm4(Pb, bia[1], A1, 512, Kp[2] / 4, true, true, true);    // stride 512 == Kp[2]
    gemmB(A1, Kp[2], 2, nullptr, Pb, 256, false, false, true);
    spmm4(Pb, bia[2], A1, 256, Kp[3] / 4, true, true, true);    // stride 256 == Kp[3]
    gemmB(A1, Kp[3], 3, nullptr, Pb, 16, false, false, true);
    spmm4(Pb, bia[3], Z, 16, 4, false, true, false);            // z, f32, no relu

    // ---- decoder: agg first (cheap dim), then gemm(+bias, relu) ----
    spmm_f<false, false, true><<<M, 64, 0, stream>>>(Z, cnt, ecv, nullptr, A1, 4, Kp[4] / 4);
    gemmB(A1, Kp[4], 4, bia[4], Pb, 256, true, true, true);
    spmm4(Pb, nullptr, A1, 256, Kp[5] / 4, false, false, true);
    gemmB(A1, Kp[5], 5, bia[5], Pb, 512, true, true, true);
    spmm4(Pb, nullptr, A1, 512, Kp[6] / 4, false, false, true);
    gemmB(A1, Kp[6], 6, bia[6], Pb, 1024, true, true, true);
    spmm4(Pb, nullptr, A1, 1024, Kp[7] / 4, false, false, true);
    gemmB(A1, Kp[7], 7, bia[7], XR, 3703, false, true, false);  // x_recon, f32 (+bias)
    return;
  }

  // ---------------- fallback: f32 activations, register-staged GEMM ----------------
  char* p = (char*)d_ws;
  auto alloc = [&](size_t bytes) { char* r = p; p += al(bytes); return r; };
  unsigned short* Wt[8];
  for (int i = 0; i < 8; ++i) Wt[i] = (unsigned short*)alloc((size_t)Nd[i] * Kp[i] * 2);
  int*  cnt = (int*)alloc(cntB);
  int2* ecv = (int2*)alloc(ecvB);
  float* P  = (float*)alloc((size_t)M * 1024 * 4);
  size_t used = (size_t)(p - (char*)d_ws);
  bool useXbf = (used + xbfB) <= ws_size;
  unsigned short* Xbf = useXbf ? (unsigned short*)alloc(xbfB) : nullptr;
  float* Q = (float*)d_out + (size_t)M * 16;

  hipMemsetAsync(cnt, 0, (size_t)M * 4, stream);
  ell_build<<<(E + 255) / 256, 256, 0, stream>>>(erows, ecols_in, evals_in, cnt, ecv, E);
  for (int i = 0; i < 8; ++i) {
    dim3 g((Kp[i] + 31) / 32, (Nd[i] + 31) / 32);
    transpose_cast<<<g, dim3(32, 8), 0, stream>>>(w[i], Wt[i], Kd[i], Nd[i], Kp[i]);
  }
  if (useXbf) {
    dim3 g((Kp[0] / 4 + 255) / 256, M);
    cast_pad_bf16<<<g, 256, 0, stream>>>(x, Xbf, M, IN_DIM, Kp[0]);
  }
  auto gemm = [&](const void* A, int li, const float* bb, float* C,
                  bool relu, bool bias_on, bool abf) {
    dim3 g((M + 127) / 128, (Nd[li] + 127) / 128);
    int K = abf ? Kp[li] : Kd[li];
    if (abf) {
      if (relu)         gemm_old<true, true, true><<<g, 256, 0, stream>>>(A, Wt[li], bb, C, M, K, Kp[li], Nd[li]);
      else if (bias_on) gemm_old<false, true, true><<<g, 256, 0, stream>>>(A, Wt[li], bb, C, M, K, Kp[li], Nd[li]);
      else              gemm_old<false, false, true><<<g, 256, 0, stream>>>(A, Wt[li], nullptr, C, M, K, Kp[li], Nd[li]);
    } else {
      if (relu)         gemm_old<true, true, false><<<g, 256, 0, stream>>>(A, Wt[li], bb, C, M, K, Kp[li], Nd[li]);
      else if (bias_on) gemm_old<false, true, false><<<g, 256, 0, stream>>>(A, Wt[li], bb, C, M, K, Kp[li], Nd[li]);
      else              gemm_old<false, false, false><<<g, 256, 0, stream>>>(A, Wt[li], nullptr, C, M, K, Kp[li], Nd[li]);
    }
  };
  auto spmm = [&](const float* S, const float* bb, float* out, int dim, bool relu, bool bias_on) {
    int nv = dim >> 2;
    int thr = nv < 64 ? 64 : (nv > 256 ? 256 : nv);
    if (relu)         spmm_f<true, true, false><<<M, thr, 0, stream>>>(S, cnt, ecv, bb, out, nv, nv);
    else if (bias_on) spmm_f<false, true, false><<<M, thr, 0, stream>>>(S, cnt, ecv, bb, out, nv, nv);
    else              spmm_f<false, false, false><<<M, thr, 0, stream>>>(S, cnt, ecv, nullptr, out, nv, nv);
  };

  if (useXbf) gemm(Xbf, 0, nullptr, P, false, false, true);
  else        gemm(x,   0, nullptr, P, false, false, false);
  spmm(P, bia[0], Q, 1024, true,  true);
  gemm(Q, 1, nullptr, P, false, false, false);  spmm(P, bia[1], Q,  512, true,  true);
  gemm(Q, 2, nullptr, P, false, false, false);  spmm(P, bia[2], Q,  256, true,  true);
  gemm(Q, 3, nullptr, P, false, false, false);  spmm(P, bia[3], Z,   16, false, true);
  spmm(Z, nullptr, P,   16, false, false);  gemm(P, 4, bia[4], Q, true,  true, false);
  spmm(Q, nullptr, P,  256, false, false);  gemm(P, 5, bia[5], Q, true,  true, false);
  spmm(Q, nullptr, P,  512, false, false);  gemm(P, 6, bia[6], Q, true,  true, false);
  spmm(Q, nullptr, P, 1024, false, false);  gemm(P, 7, bia[7], XR, false, true, false);
}

// Round 15
// 1454.149 us; speedup vs baseline: 1.0360x; 1.0360x over previous
//
#include <hip/hip_runtime.h>

#define CAP 128   // padded-ELL row capacity; max degree ~60 for Poisson(32)

typedef __bf16 bf16x8 __attribute__((ext_vector_type(8)));
typedef float  f32x4  __attribute__((ext_vector_type(4)));

__device__ __forceinline__ unsigned short f2bf(float f) {
  unsigned int u = __float_as_uint(f);
  unsigned int r = (u + 0x7FFFu + ((u >> 16) & 1u)) >> 16;
  return (unsigned short)r;
}
__device__ __forceinline__ float bf2f(unsigned short u) {
  return __uint_as_float(((unsigned int)u) << 16);
}
__device__ __forceinline__ void gload_lds16(const void* g, void* l) {
  __builtin_amdgcn_global_load_lds(
      (const __attribute__((address_space(1))) unsigned int*)g,
      (__attribute__((address_space(3))) unsigned int*)l, 16, 0, 0);
}

// ---------------- x cast+pad: X[M][K] f32 -> Xb[M][Kp] bf16, zero-padded (vectorized x4) ----
__global__ __launch_bounds__(256)
void cast_pad_bf16(const float* __restrict__ X, unsigned short* __restrict__ Xb,
                   int M, int K, int Kp) {
  int k4 = blockIdx.x * 256 + threadIdx.x;      // index in units of 4 elems
  int r = blockIdx.y;
  int k = k4 * 4;
  if (k >= Kp) return;
  ushort4 o;
  if (k + 4 <= K) {
    float4 v = *reinterpret_cast<const float4*>(X + (size_t)r * K + k);
    o.x = f2bf(v.x); o.y = f2bf(v.y); o.z = f2bf(v.z); o.w = f2bf(v.w);
  } else {
    float vv[4];
    #pragma unroll
    for (int j = 0; j < 4; ++j) vv[j] = (k + j < K) ? X[(size_t)r * K + k + j] : 0.f;
    o.x = f2bf(vv[0]); o.y = f2bf(vv[1]); o.z = f2bf(vv[2]); o.w = f2bf(vv[3]);
  }
  *reinterpret_cast<ushort4*>(Xb + (size_t)r * Kp + k) = o;
}

// ---------------- weight transpose + cast:  W[K][Nv] f32 -> Wt[Nv][Kp] bf16 ----
__global__ __launch_bounds__(256)
void transpose_cast(const float* __restrict__ W, unsigned short* __restrict__ Wt,
                    int K, int Nv, int Kp) {
  __shared__ float tile[32][33];
  int kb = blockIdx.x * 32, nb = blockIdx.y * 32;
  int tx = threadIdx.x, ty = threadIdx.y;   // 32 x 8
  for (int i = ty; i < 32; i += 8) {
    int k = kb + i, n = nb + tx;
    tile[i][tx] = (k < K && n < Nv) ? W[(size_t)k * Nv + n] : 0.f;
  }
  __syncthreads();
  for (int i = ty; i < 32; i += 8) {
    int n = nb + i, k = kb + tx;
    if (n < Nv && k < Kp) Wt[(size_t)n * Kp + k] = f2bf(tile[tx][i]);
  }
}

// ---------------- padded-ELL build (packed col+val) ----------------
__global__ __launch_bounds__(256)
void ell_build(const int* __restrict__ erows, const int* __restrict__ ecols,
               const float* __restrict__ evals, int* __restrict__ cnt,
               int2* __restrict__ ecv, int E) {
  int e = blockIdx.x * 256 + threadIdx.x;
  if (e >= E) return;
  int r = erows[e];
  int slot = atomicAdd(&cnt[r], 1);
  if (slot < CAP)
    ecv[(size_t)r * CAP + slot] = make_int2(ecols[e], __float_as_int(evals[e]));
}

// ---------------- SpMM, bf16 gather, 4 elems/thread, 8x-unrolled gather ----
template<bool RELU, bool BIAS, bool OUTBF>
__global__ __launch_bounds__(256)
void spmm_b(const unsigned short* __restrict__ S, const int* __restrict__ cnt,
            const int2* __restrict__ ecv, const float* __restrict__ bias,
            void* __restrict__ outp, int nv /*dim/4*/, int ldo4) {
  __shared__ int2 eb[CAP];
  int r = blockIdx.x, t = threadIdx.x, nt = blockDim.x;
  int c = cnt[r]; if (c > CAP) c = CAP;
  for (int j = t; j < c; j += nt) eb[j] = ecv[(size_t)r * CAP + j];
  __syncthreads();
  if (t >= nv) {
    if (OUTBF && t < ldo4) {  // zero K-pad columns for the consuming GEMM
      ushort4 z; z.x = z.y = z.z = z.w = 0;
      ((ushort4*)outp)[(size_t)r * ldo4 + t] = z;
    }
    return;
  }
  const ushort4* S4 = (const ushort4*)S;
  float ax = 0.f, ay = 0.f, az = 0.f, aw = 0.f;
  int j = 0;
  for (; j + 8 <= c; j += 8) {   // 8 independent gathers in flight (L3-latency MLP)
    ushort4 s[8]; float v[8];
    #pragma unroll
    for (int q = 0; q < 8; ++q) {
      int2 e = eb[j + q];
      s[q] = S4[(size_t)e.x * nv + t];
      v[q] = __int_as_float(e.y);
    }
    #pragma unroll
    for (int q = 0; q < 8; ++q) {
      ax += v[q] * bf2f(s[q].x); ay += v[q] * bf2f(s[q].y);
      az += v[q] * bf2f(s[q].z); aw += v[q] * bf2f(s[q].w);
    }
  }
  for (; j < c; ++j) {
    int col = eb[j].x; float v = __int_as_float(eb[j].y);
    ushort4 s = S4[(size_t)col * nv + t];
    ax += v * bf2f(s.x); ay += v * bf2f(s.y); az += v * bf2f(s.z); aw += v * bf2f(s.w);
  }
  if (BIAS) {
    float4 bb = ((const float4*)bias)[t];
    ax += bb.x; ay += bb.y; az += bb.z; aw += bb.w;
  }
  if (RELU) { ax = fmaxf(ax, 0.f); ay = fmaxf(ay, 0.f); az = fmaxf(az, 0.f); aw = fmaxf(aw, 0.f); }
  if (OUTBF) {
    ushort4 o; o.x = f2bf(ax); o.y = f2bf(ay); o.z = f2bf(az); o.w = f2bf(aw);
    ((ushort4*)outp)[(size_t)r * ldo4 + t] = o;
  } else {
    ((float4*)outp)[(size_t)r * nv + t] = make_float4(ax, ay, az, aw);
  }
}

// ---------------- SpMM, f32 gather ----------------
template<bool RELU, bool BIAS, bool OUTBF>
__global__ __launch_bounds__(256)
void spmm_f(const float* __restrict__ S, const int* __restrict__ cnt,
            const int2* __restrict__ ecv, const float* __restrict__ bias,
            void* __restrict__ outp, int nv, int ldo4) {
  __shared__ int2 eb[CAP];
  int r = blockIdx.x, t = threadIdx.x, nt = blockDim.x;
  int c = cnt[r]; if (c > CAP) c = CAP;
  for (int j = t; j < c; j += nt) eb[j] = ecv[(size_t)r * CAP + j];
  __syncthreads();
  if (t >= nv) {
    if (OUTBF && t < ldo4) {
      ushort4 z; z.x = z.y = z.z = z.w = 0;
      ((ushort4*)outp)[(size_t)r * ldo4 + t] = z;
    }
    return;
  }
  const float4* S4 = (const float4*)S;
  float ax = 0.f, ay = 0.f, az = 0.f, aw = 0.f;
  for (int j = 0; j < c; ++j) {
    int col = eb[j].x; float v = __int_as_float(eb[j].y);
    float4 s = S4[(size_t)col * nv + t];
    ax += v * s.x; ay += v * s.y; az += v * s.z; aw += v * s.w;
  }
  if (BIAS) {
    float4 bb = ((const float4*)bias)[t];
    ax += bb.x; ay += bb.y; az += bb.z; aw += bb.w;
  }
  if (RELU) { ax = fmaxf(ax, 0.f); ay = fmaxf(ay, 0.f); az = fmaxf(az, 0.f); aw = fmaxf(aw, 0.f); }
  if (OUTBF) {
    ushort4 o; o.x = f2bf(ax); o.y = f2bf(ay); o.z = f2bf(az); o.w = f2bf(aw);
    ((ushort4*)outp)[(size_t)r * ldo4 + t] = o;
  } else {
    ((float4*)outp)[(size_t)r * nv + t] = make_float4(ax, ay, az, aw);
  }
}

// ---------------- GEMM (128x128, BK=32, r10-proven): C = A[M][K]bf16 @ Bt[Nv][K]^T ----
// 512 threads / 8 waves (64x32 quadrant each, acc[4][2]) -> ~19 waves/CU at 48 KB LDS.
// Depth-3 counted-vmcnt pipeline (T4): raw s_barrier + s_waitcnt vmcnt(2).
// r8-verified both-sides XOR swizzle (0 bank conflicts). Orientation OUTPUT-conditional.
// T5 setprio around MFMA cluster. grid.x padded to 8 (stable n->XCD slice).
// [Structural A/B history: BK=64 (r5/r6), 2-phase dbuf (r6), 128x256 wide (r11),
//  256x128 tall (r14) all lose to this config -- resident-wave latency hiding and
//  per-XCD L2 footprint dominate arithmetic-intensity gains at this operating point.]
template<bool RELU, bool BIAS, bool OUTBF>
__global__ __launch_bounds__(512)
void gemm_bf16(const unsigned short* __restrict__ A, int LDA,
               const unsigned short* __restrict__ Bt, int LDB,
               const float* __restrict__ bias, void* __restrict__ Cp, int LDC,
               int M, int Nv, int NBX, int K) {
  if ((int)blockIdx.x >= NBX) return;
  __shared__ unsigned short As[3][128 * 32];
  __shared__ unsigned short Bs[3][128 * 32];
  int n0 = blockIdx.x * 128, m0 = blockIdx.y * 128;
  int t = threadIdx.x, w = t >> 6, l = t & 63;
  int wr = (w >> 2) * 64;        // 2 wave-rows (M)
  int wc = (w & 3) * 32;         // 4 wave-cols (N)
  int lr = l & 15, lhi = l >> 4;

  f32x4 acc[4][2] = {};

  int scol = ((t & 3) ^ ((t >> 3) & 3)) * 8;
  const unsigned short* ga0 = A + (size_t)(m0 + (t >> 2)) * LDA + scol;
  const unsigned short* gb0 = Bt + (size_t)(n0 + (t >> 2)) * LDB + scol;

  int nk = K >> 5;

#define STAGE(tile, Ab, Bb) do {                                \
    gload_lds16(ga0 + (size_t)(tile) * 32, (Ab) + t * 8);       \
    gload_lds16(gb0 + (size_t)(tile) * 32, (Bb) + t * 8);       \
  } while (0)

  STAGE(0, As[0], Bs[0]);
  if (nk > 1) STAGE(1, As[1], Bs[1]);

  int c0 = 0, c1 = 1, c2 = 2;
  for (int kt = 0; kt < nk; ++kt) {
    if (kt + 1 < nk) asm volatile("s_waitcnt vmcnt(2)" ::: "memory");
    else             asm volatile("s_waitcnt vmcnt(0)" ::: "memory");
    __builtin_amdgcn_sched_barrier(0);
    __builtin_amdgcn_s_barrier();
    __builtin_amdgcn_sched_barrier(0);
    if (kt + 2 < nk) STAGE(kt + 2, As[c2], Bs[c2]);

    const unsigned short* Ab = As[c0];
    const unsigned short* Bb = Bs[c0];
    bf16x8 af[4], bfr[2];
    int rchunk = (lhi ^ ((lr >> 1) & 3)) * 8;
    #pragma unroll
    for (int i = 0; i < 4; ++i) af[i] = *(const bf16x8*)&Ab[(wr + i * 16 + lr) * 32 + rchunk];
    #pragma unroll
    for (int j = 0; j < 2; ++j) bfr[j] = *(const bf16x8*)&Bb[(wc + j * 16 + lr) * 32 + rchunk];
    __builtin_amdgcn_s_setprio(1);
    #pragma unroll
    for (int i = 0; i < 4; ++i)
      #pragma unroll
      for (int j = 0; j < 2; ++j) {
        if (OUTBF)
          acc[i][j] = __builtin_amdgcn_mfma_f32_16x16x32_bf16(bfr[j], af[i], acc[i][j], 0, 0, 0);
        else
          acc[i][j] = __builtin_amdgcn_mfma_f32_16x16x32_bf16(af[i], bfr[j], acc[i][j], 0, 0, 0);
      }
    __builtin_amdgcn_s_setprio(0);

    int tmp = c0; c0 = c1; c1 = c2; c2 = tmp;
  }
#undef STAGE

  if (OUTBF) {
    #pragma unroll
    for (int i = 0; i < 4; ++i) {
      int grow = m0 + wr + i * 16 + lr;
      if (grow >= M) continue;
      #pragma unroll
      for (int j = 0; j < 2; ++j) {
        int gcol = n0 + wc + j * 16 + lhi * 4;
        if (gcol >= Nv) continue;
        f32x4 v = acc[i][j];
        float v0 = v[0], v1 = v[1], v2 = v[2], v3 = v[3];
        if (BIAS) { v0 += bias[gcol]; v1 += bias[gcol + 1]; v2 += bias[gcol + 2]; v3 += bias[gcol + 3]; }
        if (RELU) { v0 = fmaxf(v0, 0.f); v1 = fmaxf(v1, 0.f); v2 = fmaxf(v2, 0.f); v3 = fmaxf(v3, 0.f); }
        ushort4 o; o.x = f2bf(v0); o.y = f2bf(v1); o.z = f2bf(v2); o.w = f2bf(v3);
        *(ushort4*)((unsigned short*)Cp + (size_t)grow * LDC + gcol) = o;
      }
    }
  } else {
    int cr = lhi * 4, cc = lr;
    #pragma unroll
    for (int i = 0; i < 4; ++i) {
      #pragma unroll
      for (int j = 0; j < 2; ++j) {
        int gcol = n0 + wc + j * 16 + cc;
        if (gcol >= Nv) continue;
        float bv = BIAS ? bias[gcol] : 0.f;
        #pragma unroll
        for (int q = 0; q < 4; ++q) {
          int grow = m0 + wr + i * 16 + cr + q;
          if (grow >= M) continue;
          float v = acc[i][j][q] + bv;
          if (RELU) v = fmaxf(v, 0.f);
          ((float*)Cp)[(size_t)grow * LDC + gcol] = v;
        }
      }
    }
  }
}

// ---------------- fallback GEMM (register staging) ----------------
template<bool RELU, bool BIAS, bool ABF>
__global__ __launch_bounds__(256)
void gemm_old(const void* __restrict__ Ap, const unsigned short* __restrict__ Bt,
              const float* __restrict__ bias, float* __restrict__ C,
              int M, int K, int Kp, int Nv) {
  __shared__ unsigned short As[128][40];
  __shared__ unsigned short Bs[128][40];
  int m0 = blockIdx.x * 128, n0 = blockIdx.y * 128;
  int t = threadIdx.x;
  int w = t >> 6, l = t & 63;
  int wr = (w >> 1) * 64, wc = (w & 1) * 64;
  int lr = l & 15, lk = (l >> 4) * 8;
  f32x4 acc[4][4] = {};
  int srow = t >> 1;
  int skg  = (t & 1) * 16;
  int nk = (K + 31) / 32;
  for (int kt = 0; kt < nk; ++kt) {
    int k0 = kt * 32;
    {
      int gm = m0 + srow;
      unsigned short* dst = &As[srow][skg];
      if (ABF) {
        uint4 v0 = make_uint4(0,0,0,0), v1 = make_uint4(0,0,0,0);
        if (gm < M) {
          const uint4* src = reinterpret_cast<const uint4*>(
              (const unsigned short*)Ap + (size_t)gm * Kp + k0 + skg);
          v0 = src[0]; v1 = src[1];
        }
        reinterpret_cast<uint4*>(dst)[0] = v0;
        reinterpret_cast<uint4*>(dst)[1] = v1;
      } else {
        const float* A = (const float*)Ap;
        const float* src = A + (size_t)gm * K + k0 + skg;
        if (gm < M && (K & 3) == 0 && k0 + skg + 16 <= K) {
          #pragma unroll
          for (int j = 0; j < 4; ++j) {
            float4 v = reinterpret_cast<const float4*>(src)[j];
            unsigned int lo = (unsigned int)f2bf(v.x) | ((unsigned int)f2bf(v.y) << 16);
            unsigned int hi = (unsigned int)f2bf(v.z) | ((unsigned int)f2bf(v.w) << 16);
            reinterpret_cast<uint2*>(dst)[j] = make_uint2(lo, hi);
          }
        } else {
          for (int j = 0; j < 16; ++j) {
            int k = k0 + skg + j;
            float v = (gm < M && k < K) ? A[(size_t)gm * K + k] : 0.f;
            dst[j] = f2bf(v);
          }
        }
      }
    }
    {
      int gn = n0 + srow;
      unsigned short* dst = &Bs[srow][skg];
      if (gn < Nv && k0 + skg + 16 <= Kp) {
        const uint4* src = reinterpret_cast<const uint4*>(Bt + (size_t)gn * Kp + k0 + skg);
        reinterpret_cast<uint4*>(dst)[0] = src[0];
        reinterpret_cast<uint4*>(dst)[1] = src[1];
      } else {
        for (int j = 0; j < 16; ++j) {
          int k = k0 + skg + j;
          dst[j] = (gn < Nv && k < Kp) ? Bt[(size_t)gn * Kp + k] : (unsigned short)0;
        }
      }
    }
    __syncthreads();
    bf16x8 a[4], b[4];
    #pragma unroll
    for (int i = 0; i < 4; ++i) a[i] = *reinterpret_cast<const bf16x8*>(&As[wr + i * 16 + lr][lk]);
    #pragma unroll
    for (int j = 0; j < 4; ++j) b[j] = *reinterpret_cast<const bf16x8*>(&Bs[wc + j * 16 + lr][lk]);
    #pragma unroll
    for (int i = 0; i < 4; ++i)
      #pragma unroll
      for (int j = 0; j < 4; ++j)
        acc[i][j] = __builtin_amdgcn_mfma_f32_16x16x32_bf16(a[i], b[j], acc[i][j], 0, 0, 0);
    __syncthreads();
  }
  int cr = (l >> 4) * 4, cc = l & 15;
  #pragma unroll
  for (int i = 0; i < 4; ++i) {
    #pragma unroll
    for (int j = 0; j < 4; ++j) {
      int gcol = n0 + wc + j * 16 + cc;
      if (gcol >= Nv) continue;
      float bv = BIAS ? bias[gcol] : 0.f;
      #pragma unroll
      for (int q = 0; q < 4; ++q) {
        int grow = m0 + wr + i * 16 + cr + q;
        if (grow >= M) continue;
        float v = acc[i][j][q] + bv;
        if (RELU) v = fmaxf(v, 0.f);
        C[(size_t)grow * Nv + gcol] = v;
      }
    }
  }
}

// ------------------------------------------------------------------------------------
extern "C" void kernel_launch(void* const* d_in, const int* in_sizes, int n_in,
                              void* d_out, int out_size, void* d_ws, size_t ws_size,
                              hipStream_t stream) {
  const float* x        = (const float*)d_in[0];
  const int*   erows    = (const int*)d_in[1];
  const int*   ecols_in = (const int*)d_in[2];
  const float* evals_in = (const float*)d_in[3];
  const float* w[8]; const float* bia[8];
  for (int i = 0; i < 8; ++i) { w[i] = (const float*)d_in[4 + 2 * i]; bia[i] = (const float*)d_in[5 + 2 * i]; }

  const int IN_DIM = 3703;
  const int M = in_sizes[0] / IN_DIM;       // 20000
  const int E = in_sizes[1];                // 640000
  const int Kd[8] = {3703, 1024, 512, 256,   16, 256, 512, 1024};
  const int Nd[8] = {1024,  512, 256,  16,  256, 512, 1024, 3703};
  int Kp[8], Nvp[8];
  for (int i = 0; i < 8; ++i) { Kp[i] = (Kd[i] + 63) & ~63; Nvp[i] = (Nd[i] + 127) & ~127; }

  auto al = [](size_t v) { return (v + 255) & ~(size_t)255; };
  size_t wtB[8], wtTot = 0;
  for (int i = 0; i < 8; ++i) { wtB[i] = al((size_t)Nvp[i] * Kp[i] * 2); wtTot += wtB[i]; }
  size_t cntB = al((size_t)M * 4), ecvB = al((size_t)M * CAP * 8);
  size_t xbfB = al((size_t)M * Kp[0] * 2);
  size_t a1B  = al((size_t)M * 1024 * 2);
  size_t pbB  = al((size_t)M * 1024 * 2);
  size_t grdB = 1 << 20;
  bool fast = (wtTot + cntB + ecvB + xbfB + a1B + pbB + grdB) <= ws_size;

  float* Z  = (float*)d_out;                    // M x 16
  float* XR = (float*)d_out + (size_t)M * 16;   // M x 3703

  if (fast) {
    char* p = (char*)d_ws;
    auto alloc = [&](size_t bytes) { char* r = p; p += al(bytes); return r; };
    unsigned short* Wt[8];
    for (int i = 0; i < 8; ++i) Wt[i] = (unsigned short*)alloc(wtB[i]);
    int*  cnt = (int*)alloc(cntB);
    int2* ecv = (int2*)alloc(ecvB);
    unsigned short* Xbf = (unsigned short*)alloc(xbfB);  // m-tail OOB reads spill into A1
    unsigned short* A1  = (unsigned short*)alloc(a1B);   // ... into Pb
    unsigned short* Pb  = (unsigned short*)alloc(pbB);   // ... into guard
    alloc(grdB);

    hipMemsetAsync(cnt, 0, (size_t)M * 4, stream);
    ell_build<<<(E + 255) / 256, 256, 0, stream>>>(erows, ecols_in, evals_in, cnt, ecv, E);
    for (int i = 0; i < 8; ++i) {
      dim3 g((Kp[i] + 31) / 32, (Nd[i] + 31) / 32);
      transpose_cast<<<g, dim3(32, 8), 0, stream>>>(w[i], Wt[i], Kd[i], Nd[i], Kp[i]);
    }
    { dim3 g((Kp[0] / 4 + 255) / 256, M);
      cast_pad_bf16<<<g, 256, 0, stream>>>(x, Xbf, M, IN_DIM, Kp[0]); }

    auto gemmB = [&](const unsigned short* A, int lda, int li, const float* bb,
                     void* C, int ldc, bool relu, bool bias_on, bool outbf) {
      int nbx = (Nd[li] + 127) / 128;
      dim3 g((unsigned)((nbx + 7) & ~7), (unsigned)((M + 127) / 128));  // x padded: stable n->XCD
      if (outbf) {
        if (relu)
          gemm_bf16<true, true, true><<<g, 512, 0, stream>>>(A, lda, Wt[li], Kp[li], bb, C, ldc, M, Nd[li], nbx, Kp[li]);
        else
          gemm_bf16<false, false, true><<<g, 512, 0, stream>>>(A, lda, Wt[li], Kp[li], nullptr, C, ldc, M, Nd[li], nbx, Kp[li]);
      } else {
        gemm_bf16<false, true, false><<<g, 512, 0, stream>>>(A, lda, Wt[li], Kp[li], bb, C, ldc, M, Nd[li], nbx, Kp[li]);
      }
    };
    auto spmm4 = [&](const unsigned short* S, const float* bb, void* out,
                     int dim, int ldo4, bool relu, bool bias_on, bool outbf) {
      int nv = dim >> 2;
      int thr = (nv > ldo4 ? nv : ldo4); thr = (thr + 63) & ~63; if (thr > 256) thr = 256;
      if (outbf) {
        if (relu) spmm_b<true, true, true><<<M, thr, 0, stream>>>(S, cnt, ecv, bb, out, nv, ldo4);
        else      spmm_b<false, false, true><<<M, thr, 0, stream>>>(S, cnt, ecv, nullptr, out, nv, ldo4);
      } else {
        spmm_b<false, true, false><<<M, thr, 0, stream>>>(S, cnt, ecv, bb, out, nv, nv);
      }
    };

    // ---- encoder: support = H@W (bf16), agg = A*support (+bias, relu, bf16) ----
    gemmB(Xbf, Kp[0], 0, nullptr, Pb, 1024, false, false, true);
    spmm4(Pb, bia[0], A1, 1024, Kp[1] / 4, true, true, true);   // stride 1024 == Kp[1]
    gemmB(A1, Kp[1], 1, nullptr, Pb, 512, false, false, true);
    spmm4(Pb, bia[1], A1, 512, Kp[2] / 4, true, true, true);    // stride 512 == Kp[2]
    gemmB(A1, Kp[2], 2, nullptr, Pb, 256, false, false, true);
    spmm4(Pb, bia[2], A1, 256, Kp[3] / 4, true, true, true);    // stride 256 == Kp[3]
    gemmB(A1, Kp[3], 3, nullptr, Pb, 16, false, false, true);
    spmm4(Pb, bia[3], Z, 16, 4, false, true, false);            // z, f32, no relu

    // ---- decoder: agg first (cheap dim), then gemm(+bias, relu) ----
    spmm_f<false, false, true><<<M, 64, 0, stream>>>(Z, cnt, ecv, nullptr, A1, 4, Kp[4] / 4);
    gemmB(A1, Kp[4], 4, bia[4], Pb, 256, true, true, true);
    spmm4(Pb, nullptr, A1, 256, Kp[5] / 4, false, false, true);
    gemmB(A1, Kp[5], 5, bia[5], Pb, 512, true, true, true);
    spmm4(Pb, nullptr, A1, 512, Kp[6] / 4, false, false, true);
    gemmB(A1, Kp[6], 6, bia[6], Pb, 1024, true, true, true);
    spmm4(Pb, nullptr, A1, 1024, Kp[7] / 4, false, false, true);
    gemmB(A1, Kp[7], 7, bia[7], XR, 3703, false, true, false);  // x_recon, f32 (+bias)
    return;
  }

  // ---------------- fallback: f32 activations, register-staged GEMM ----------------
  char* p = (char*)d_ws;
  auto alloc = [&](size_t bytes) { char* r = p; p += al(bytes); return r; };
  unsigned short* Wt[8];
  for (int i = 0; i < 8; ++i) Wt[i] = (unsigned short*)alloc((size_t)Nd[i] * Kp[i] * 2);
  int*  cnt = (int*)alloc(cntB);
  int2* ecv = (int2*)alloc(ecvB);
  float* P  = (float*)alloc((size_t)M * 1024 * 4);
  size_t used = (size_t)(p - (char*)d_ws);
  bool useXbf = (used + xbfB) <= ws_size;
  unsigned short* Xbf = useXbf ? (unsigned short*)alloc(xbfB) : nullptr;
  float* Q = (float*)d_out + (size_t)M * 16;

  hipMemsetAsync(cnt, 0, (size_t)M * 4, stream);
  ell_build<<<(E + 255) / 256, 256, 0, stream>>>(erows, ecols_in, evals_in, cnt, ecv, E);
  for (int i = 0; i < 8; ++i) {
    dim3 g((Kp[i] + 31) / 32, (Nd[i] + 31) / 32);
    transpose_cast<<<g, dim3(32, 8), 0, stream>>>(w[i], Wt[i], Kd[i], Nd[i], Kp[i]);
  }
  if (useXbf) {
    dim3 g((Kp[0] / 4 + 255) / 256, M);
    cast_pad_bf16<<<g, 256, 0, stream>>>(x, Xbf, M, IN_DIM, Kp[0]);
  }
  auto gemm = [&](const void* A, int li, const float* bb, float* C,
                  bool relu, bool bias_on, bool abf) {
    dim3 g((M + 127) / 128, (Nd[li] + 127) / 128);
    int K = abf ? Kp[li] : Kd[li];
    if (abf) {
      if (relu)         gemm_old<true, true, true><<<g, 256, 0, stream>>>(A, Wt[li], bb, C, M, K, Kp[li], Nd[li]);
      else if (bias_on) gemm_old<false, true, true><<<g, 256, 0, stream>>>(A, Wt[li], bb, C, M, K, Kp[li], Nd[li]);
      else              gemm_old<false, false, true><<<g, 256, 0, stream>>>(A, Wt[li], nullptr, C, M, K, Kp[li], Nd[li]);
    } else {
      if (relu)         gemm_old<true, true, false><<<g, 256, 0, stream>>>(A, Wt[li], bb, C, M, K, Kp[li], Nd[li]);
      else if (bias_on) gemm_old<false, true, false><<<g, 256, 0, stream>>>(A, Wt[li], bb, C, M, K, Kp[li], Nd[li]);
      else              gemm_old<false, false, false><<<g, 256, 0, stream>>>(A, Wt[li], nullptr, C, M, K, Kp[li], Nd[li]);
    }
  };
  auto spmm = [&](const float* S, const float* bb, float* out, int dim, bool relu, bool bias_on) {
    int nv = dim >> 2;
    int thr = nv < 64 ? 64 : (nv > 256 ? 256 : nv);
    if (relu)         spmm_f<true, true, false><<<M, thr, 0, stream>>>(S, cnt, ecv, bb, out, nv, nv);
    else if (bias_on) spmm_f<false, true, false><<<M, thr, 0, stream>>>(S, cnt, ecv, bb, out, nv, nv);
    else              spmm_f<false, false, false><<<M, thr, 0, stream>>>(S, cnt, ecv, nullptr, out, nv, nv);
  };

  if (useXbf) gemm(Xbf, 0, nullptr, P, false, false, true);
  else        gemm(x,   0, nullptr, P, false, false, false);
  spmm(P, bia[0], Q, 1024, true,  true);
  gemm(Q, 1, nullptr, P, false, false, false);  spmm(P, bia[1], Q,  512, true,  true);
  gemm(Q, 2, nullptr, P, false, false, false);  spmm(P, bia[2], Q,  256, true,  true);
  gemm(Q, 3, nullptr, P, false, false, false);  spmm(P, bia[3], Z,   16, false, true);
  spmm(Z, nullptr, P,   16, false, false);  gemm(P, 4, bia[4], Q, true,  true, false);
  spmm(Q, nullptr, P,  256, false, false);  gemm(P, 5, bia[5], Q, true,  true, false);
  spmm(Q, nullptr, P,  512, false, false);  gemm(P, 6, bia[6], Q, true,  true, false);
  spmm(Q, nullptr, P, 1024, false, false);  gemm(P, 7, bia[7], XR, false, true, false);
}